// Round 4
// baseline (76.779 us; speedup 1.0000x reference)
//
#include <hip/hip_runtime.h>

#define NQ   131072
#define PCNT 2048
#define NBIN 4096
#define NCH  4
#define RPC  (PCNT / NCH)   /* 512 reps per chunk */
#define QPT  4              /* queries per thread in k_main */

// ws layout (bytes)
#define HIST_OFF 0                         /* NBIN*4 = 16384 */
#define CTRL_OFF 16384                     /* 256 B  */
#define KEYS_OFF (16384 + 256)             /* NQ*4   */
#define CAND_OFF (KEYS_OFF + NQ * 4)       /* NQ*4   */
#define REPS_OFF (CAND_OFF + NQ * 4)       /* PCNT*16, 16B aligned */
#define PART_OFF (REPS_OFF + PCNT * 16)    /* NCH*NQ*4 */

// ctrl: [5]=curL [6]=curE [7]=cand cursor (M)

__device__ __forceinline__ float sumsq_nc(float x, float y, float z) {
#pragma clang fp contract(off)
  return x * x + y * y + z * z;
}

// 64 blocks x 256 thr x 8 pts: keys + LDS-aggregated 12-bit histogram
__global__ __launch_bounds__(256) void k_keys(const float* __restrict__ q,
                                              unsigned* __restrict__ keys,
                                              unsigned* __restrict__ hist,
                                              unsigned* __restrict__ ctrl) {
  __shared__ unsigned h[NBIN];
  int t = threadIdx.x;
  for (int j = t; j < NBIN; j += 256) h[j] = 0;
  if (blockIdx.x == 0 && t >= 5 && t < 8) ctrl[t] = 0;
  __syncthreads();
  int base = blockIdx.x * 2048 + t;
#pragma unroll
  for (int l = 0; l < 8; ++l) {
    int i = base + l * 256;
    float x = q[3 * i], y = q[3 * i + 1], z = q[3 * i + 2];
    float s = sumsq_nc(x, y, z);
    float d = sqrtf(s) - 0.5f;
    unsigned k = __float_as_uint(fabsf(d));  // nonneg float: bits monotone
    keys[i] = k;
    atomicAdd(&h[k >> 20], 1u);
  }
  __syncthreads();
  for (int j = t; j < NBIN; j += 256) {
    unsigned v = h[j];
    if (v) atomicAdd(&hist[j], v);
  }
}

// per-block coarse scan: bin B1 containing the PCNT-th smallest, C1 = #below
__device__ __forceinline__ void coarse_scan(const unsigned* __restrict__ hist,
                                            unsigned* part, unsigned* pB1,
                                            unsigned* pC1) {
  int t = threadIdx.x;
  unsigned s = 0;
  for (int j = 0; j < 16; ++j) s += hist[t * 16 + j];
  part[t] = s;
  __syncthreads();
  if (t == 0) {
    unsigned cum = 0; int c = 0;
    for (; c < 256; ++c) { if (cum + part[c] >= PCNT) break; cum += part[c]; }
    unsigned b = c * 16;
    for (;; ++b) { unsigned v = hist[b]; if (cum + v >= PCNT) break; cum += v; }
    *pB1 = b; *pC1 = cum;
  }
  __syncthreads();
}

// 64 blocks x 256 x 8: push keys with top-12 == B1 into cand (values only)
__global__ __launch_bounds__(256) void k_compact1(const unsigned* __restrict__ keys,
                                                  const unsigned* __restrict__ hist,
                                                  unsigned* __restrict__ ctrl,
                                                  unsigned* __restrict__ cand) {
  __shared__ unsigned part[256];
  __shared__ unsigned sB1, sC1;
  __shared__ unsigned tot, base, cur;
  int t = threadIdx.x;
  if (t == 0) tot = 0;
  coarse_scan(hist, part, &sB1, &sC1);
  unsigned B1 = sB1;
  int st = blockIdx.x * 256 + t;
  unsigned kk[8]; unsigned n = 0;
#pragma unroll
  for (int l = 0; l < 8; ++l) { kk[l] = keys[st + l * 16384]; n += ((kk[l] >> 20) == B1); }
  if (n) atomicAdd(&tot, n);
  __syncthreads();
  if (t == 0) { base = atomicAdd(&ctrl[7], tot); cur = 0; }
  __syncthreads();
  int lane = t & 63;
#pragma unroll
  for (int l = 0; l < 8; ++l) {
    bool m = (kk[l] >> 20) == B1;
    unsigned long long mb = __ballot(m);
    unsigned wcnt = __popcll(mb);
    if (wcnt) {
      unsigned lb = 0;
      if (lane == 0) lb = atomicAdd(&cur, wcnt);
      lb = __shfl(lb, 0);
      if (m) cand[base + lb + __popcll(mb & ((1ull << lane) - 1ull))] = kk[l];
    }
  }
}

// 64 blocks x 256 x 8: inline exact select (over cand) + build reps[]
__global__ __launch_bounds__(256) void k_repbuild(const float* __restrict__ q,
                                                  const unsigned* __restrict__ keys,
                                                  const unsigned* __restrict__ hist,
                                                  unsigned* __restrict__ ctrl,
                                                  const unsigned* __restrict__ cand,
                                                  float4* __restrict__ reps) {
  __shared__ unsigned part[256];
  __shared__ unsigned h2[NBIN];
  __shared__ unsigned h3[256];
  __shared__ unsigned sB1, sC1, sB2, sC2, sN2, sT, sCL, sK2;
  __shared__ unsigned totL, totE, curL, curE;
  int t = threadIdx.x;
  for (int j = t; j < NBIN; j += 256) h2[j] = 0;
  h3[t] = 0;
  if (t == 0) { totL = 0; totE = 0; }
  coarse_scan(hist, part, &sB1, &sC1);   // includes syncthreads
  unsigned M = ctrl[7];
  for (unsigned j = t; j < M; j += 256) atomicAdd(&h2[(cand[j] >> 8) & 0xFFFu], 1u);
  __syncthreads();
  unsigned s = 0;
  for (int j = 0; j < 16; ++j) s += h2[t * 16 + j];
  part[t] = s;
  __syncthreads();
  if (t == 0) {
    unsigned need = PCNT - sC1;
    unsigned cum = 0; int c = 0;
    for (; c < 256; ++c) { if (cum + part[c] >= need) break; cum += part[c]; }
    unsigned b = c * 16;
    for (;; ++b) { unsigned v = h2[b]; if (cum + v >= need) break; cum += v; }
    sB2 = b; sC2 = cum; sN2 = need - cum;
  }
  __syncthreads();
  unsigned b2 = sB2;
  for (unsigned j = t; j < M; j += 256) {
    unsigned k = cand[j];
    if (((k >> 8) & 0xFFFu) == b2) atomicAdd(&h3[k & 0xFFu], 1u);
  }
  __syncthreads();
  if (t == 0) {
    unsigned need2 = sN2, cum = 0, b = 0;
    for (;; ++b) { unsigned v = h3[b]; if (cum + v >= need2) break; cum += v; }
    sT = (sB1 << 20) | (b2 << 8) | b;
    sCL = sC1 + sC2 + cum;
    sK2 = PCNT - sCL;
  }
  __syncthreads();
  unsigned T = sT, CL = sCL, K2 = sK2;
  int st = blockIdx.x * 256 + t;
  unsigned kk[8]; unsigned nl = 0, ne = 0;
#pragma unroll
  for (int l = 0; l < 8; ++l) {
    kk[l] = keys[st + l * 16384];
    nl += (kk[l] < T); ne += (kk[l] == T);
  }
  if (nl) atomicAdd(&totL, nl);
  if (ne) atomicAdd(&totE, ne);
  __syncthreads();
  if (t == 0) { curL = atomicAdd(&ctrl[5], totL); curE = atomicAdd(&ctrl[6], totE); }
  __syncthreads();
  int lane = t & 63;
#pragma unroll
  for (int l = 0; l < 8; ++l) {
    int i = st + l * 16384;
    unsigned k = kk[l];
    bool lt = k < T, eq = k == T;
    unsigned long long ml = __ballot(lt), me = __ballot(eq);
    unsigned wl = __popcll(ml), we = __popcll(me);
    unsigned bl = 0, be = 0;
    if (wl) { if (lane == 0) bl = atomicAdd(&curL, wl); bl = __shfl(bl, 0); }
    if (we) { if (lane == 0) be = atomicAdd(&curE, we); be = __shfl(be, 0); }
    int pos = -1;
    if (lt) pos = (int)(bl + __popcll(ml & ((1ull << lane) - 1ull)));
    else if (eq) {
      unsigned e = be + __popcll(me & ((1ull << lane) - 1ull));
      if (e < K2) pos = (int)(CL + e);
    }
    if (pos >= 0) {
      float x = q[3 * i], y = q[3 * i + 1], z = q[3 * i + 2];
      reps[pos] = make_float4(x, y, z, sumsq_nc(x, y, z));
    }
  }
}

// grid (128, NCH) x 256: 4 queries/thread, scalar (wave-broadcast) rep loads
__global__ __launch_bounds__(256) void k_main(const float* __restrict__ q,
                                              const float4* __restrict__ reps,
                                              float* __restrict__ part) {
  int t = threadIdx.x;
  int c = blockIdx.y;
  int qbase = blockIdx.x * (256 * QPT) + t;
  const float4* rp = reps + c * RPC;
  float qx[QPT], qy[QPT], qz[QPT], mn[QPT];
#pragma unroll
  for (int k = 0; k < QPT; ++k) {
    int i = qbase + k * 256;
    qx[k] = -2.0f * q[3 * i];
    qy[k] = -2.0f * q[3 * i + 1];
    qz[k] = -2.0f * q[3 * i + 2];
    mn[k] = 1e30f;
  }
#pragma unroll 4
  for (int j = 0; j < RPC; j += 2) {
    float4 r0 = rp[j], r1 = rp[j + 1];
#pragma unroll
    for (int k = 0; k < QPT; ++k) {
      float t0 = fmaf(qx[k], r0.x, fmaf(qy[k], r0.y, fmaf(qz[k], r0.z, r0.w)));
      float t1 = fmaf(qx[k], r1.x, fmaf(qy[k], r1.y, fmaf(qz[k], r1.z, r1.w)));
      mn[k] = fminf(mn[k], fminf(t0, t1));  // fuses to v_min3_f32
    }
  }
#pragma unroll
  for (int k = 0; k < QPT; ++k) part[c * NQ + qbase + k * 256] = mn[k];
}

// 512 blocks: combine chunks + epilogue
__global__ __launch_bounds__(256) void k_reduce(const float* __restrict__ q,
                                                const float* __restrict__ part,
                                                float* __restrict__ out) {
  int i = blockIdx.x * 256 + threadIdx.x;
  float m = fminf(fminf(part[i], part[NQ + i]),
                  fminf(part[2 * NQ + i], part[3 * NQ + i]));
  float x = q[3 * i], y = q[3 * i + 1], z = q[3 * i + 2];
  float s = sumsq_nc(x, y, z);
  float d = sqrtf(s) - 0.5f;
  float d2 = fmaxf(s + m, 0.0f);
  float nd = (d2 > 0.0f) ? sqrtf(d2) : 0.0f;
  float sg = (d > 0.0f) ? 1.0f : ((d < 0.0f) ? -1.0f : 0.0f);
  out[i] = fminf(nd * sg, d);
}

extern "C" void kernel_launch(void* const* d_in, const int* in_sizes, int n_in,
                              void* d_out, int out_size, void* d_ws, size_t ws_size,
                              hipStream_t stream) {
  const float* q = (const float*)d_in[0];
  float* out = (float*)d_out;
  char* ws = (char*)d_ws;

  unsigned* hist = (unsigned*)(ws + HIST_OFF);
  unsigned* ctrl = (unsigned*)(ws + CTRL_OFF);
  unsigned* keys = (unsigned*)(ws + KEYS_OFF);
  unsigned* cand = (unsigned*)(ws + CAND_OFF);
  float4* reps   = (float4*)(ws + REPS_OFF);
  float* part    = (float*)(ws + PART_OFF);

  hipMemsetAsync(hist, 0, NBIN * 4, stream);
  k_keys<<<64, 256, 0, stream>>>(q, keys, hist, ctrl);
  k_compact1<<<64, 256, 0, stream>>>(keys, hist, ctrl, cand);
  k_repbuild<<<64, 256, 0, stream>>>(q, keys, hist, ctrl, cand, reps);
  k_main<<<dim3(NQ / (256 * QPT), NCH), 256, 0, stream>>>(q, reps, part);
  k_reduce<<<NQ / 256, 256, 0, stream>>>(q, part, out);
}

// Round 5
// 64.031 us; speedup vs baseline: 1.1991x; 1.1991x over previous
//
#include <hip/hip_runtime.h>

#define NQ   131072
#define PCNT 2048
#define NBIN 4096
#define QPT  4              /* queries per thread in k_main */

// ws layout (bytes)
#define HIST_OFF 0                         /* NBIN*4 = 16384 */
#define CTRL_OFF 16384                     /* 256 B  */
#define KEYS_OFF (16384 + 256)             /* NQ*4   */
#define CAND_OFF (KEYS_OFF + NQ * 4)       /* NQ*4   */
#define REPS_OFF (CAND_OFF + NQ * 4)       /* PCNT*16, 16B aligned */
#define PART_OFF (REPS_OFF + PCNT * 16)    /* NCH*NQ*4 */

// ctrl: [5]=curL [6]=curE [7]=cand cursor (M)

__device__ __forceinline__ float sumsq_nc(float x, float y, float z) {
#pragma clang fp contract(off)
  return x * x + y * y + z * z;
}

// 128 blocks x 256 thr x 4 pts: keys + LDS-aggregated 12-bit histogram
__global__ __launch_bounds__(256) void k_keys(const float* __restrict__ q,
                                              unsigned* __restrict__ keys,
                                              unsigned* __restrict__ hist,
                                              unsigned* __restrict__ ctrl) {
  __shared__ unsigned h[NBIN];
  int t = threadIdx.x;
  for (int j = t; j < NBIN; j += 256) h[j] = 0;
  if (blockIdx.x == 0 && t >= 5 && t < 8) ctrl[t] = 0;
  __syncthreads();
  int base = blockIdx.x * 256 + t;
#pragma unroll
  for (int l = 0; l < 4; ++l) {
    int i = base + l * 32768;
    float x = q[3 * i], y = q[3 * i + 1], z = q[3 * i + 2];
    float s = sumsq_nc(x, y, z);
    float d = sqrtf(s) - 0.5f;
    unsigned k = __float_as_uint(fabsf(d));  // nonneg float: bits monotone
    keys[i] = k;
    atomicAdd(&h[k >> 20], 1u);
  }
  __syncthreads();
  for (int j = t; j < NBIN; j += 256) {
    unsigned v = h[j];
    if (v) atomicAdd(&hist[j], v);
  }
}

// per-block coarse scan: bin B1 containing the PCNT-th smallest, C1 = #below
__device__ __forceinline__ void coarse_scan(const unsigned* __restrict__ hist,
                                            unsigned* part, unsigned* pB1,
                                            unsigned* pC1) {
  int t = threadIdx.x;
  unsigned s = 0;
  for (int j = 0; j < 16; ++j) s += hist[t * 16 + j];
  part[t] = s;
  __syncthreads();
  if (t == 0) {
    unsigned cum = 0; int c = 0;
    for (; c < 256; ++c) { if (cum + part[c] >= PCNT) break; cum += part[c]; }
    unsigned b = c * 16;
    for (;; ++b) { unsigned v = hist[b]; if (cum + v >= PCNT) break; cum += v; }
    *pB1 = b; *pC1 = cum;
  }
  __syncthreads();
}

// 128 blocks x 256 x 4: push keys with top-12 == B1 into cand (values only)
__global__ __launch_bounds__(256) void k_compact1(const unsigned* __restrict__ keys,
                                                  const unsigned* __restrict__ hist,
                                                  unsigned* __restrict__ ctrl,
                                                  unsigned* __restrict__ cand) {
  __shared__ unsigned part[256];
  __shared__ unsigned sB1, sC1;
  __shared__ unsigned tot, base, cur;
  int t = threadIdx.x;
  if (t == 0) tot = 0;
  coarse_scan(hist, part, &sB1, &sC1);
  unsigned B1 = sB1;
  int st = blockIdx.x * 256 + t;
  unsigned kk[4]; unsigned n = 0;
#pragma unroll
  for (int l = 0; l < 4; ++l) { kk[l] = keys[st + l * 32768]; n += ((kk[l] >> 20) == B1); }
  if (n) atomicAdd(&tot, n);
  __syncthreads();
  if (t == 0) { base = atomicAdd(&ctrl[7], tot); cur = 0; }
  __syncthreads();
  int lane = t & 63;
#pragma unroll
  for (int l = 0; l < 4; ++l) {
    bool m = (kk[l] >> 20) == B1;
    unsigned long long mb = __ballot(m);
    unsigned wcnt = __popcll(mb);
    if (wcnt) {
      unsigned lb = 0;
      if (lane == 0) lb = atomicAdd(&cur, wcnt);
      lb = __shfl(lb, 0);
      if (m) cand[base + lb + __popcll(mb & ((1ull << lane) - 1ull))] = kk[l];
    }
  }
}

// 128 blocks x 256 x 4: inline exact select (over cand) + build reps[]
__global__ __launch_bounds__(256) void k_repbuild(const float* __restrict__ q,
                                                  const unsigned* __restrict__ keys,
                                                  const unsigned* __restrict__ hist,
                                                  unsigned* __restrict__ ctrl,
                                                  const unsigned* __restrict__ cand,
                                                  float4* __restrict__ reps) {
  __shared__ unsigned part[256];
  __shared__ unsigned h2[NBIN];
  __shared__ unsigned h3[256];
  __shared__ unsigned sB1, sC1, sB2, sC2, sN2, sT, sCL, sK2;
  __shared__ unsigned totL, totE, curL, curE;
  int t = threadIdx.x;
  for (int j = t; j < NBIN; j += 256) h2[j] = 0;
  h3[t] = 0;
  if (t == 0) { totL = 0; totE = 0; }
  coarse_scan(hist, part, &sB1, &sC1);   // includes syncthreads
  unsigned M = ctrl[7];
  for (unsigned j = t; j < M; j += 256) atomicAdd(&h2[(cand[j] >> 8) & 0xFFFu], 1u);
  __syncthreads();
  unsigned s = 0;
  for (int j = 0; j < 16; ++j) s += h2[t * 16 + j];
  part[t] = s;
  __syncthreads();
  if (t == 0) {
    unsigned need = PCNT - sC1;
    unsigned cum = 0; int c = 0;
    for (; c < 256; ++c) { if (cum + part[c] >= need) break; cum += part[c]; }
    unsigned b = c * 16;
    for (;; ++b) { unsigned v = h2[b]; if (cum + v >= need) break; cum += v; }
    sB2 = b; sC2 = cum; sN2 = need - cum;
  }
  __syncthreads();
  unsigned b2 = sB2;
  for (unsigned j = t; j < M; j += 256) {
    unsigned k = cand[j];
    if (((k >> 8) & 0xFFFu) == b2) atomicAdd(&h3[k & 0xFFu], 1u);
  }
  __syncthreads();
  if (t == 0) {
    unsigned need2 = sN2, cum = 0, b = 0;
    for (;; ++b) { unsigned v = h3[b]; if (cum + v >= need2) break; cum += v; }
    sT = (sB1 << 20) | (b2 << 8) | b;
    sCL = sC1 + sC2 + cum;
    sK2 = PCNT - sCL;
  }
  __syncthreads();
  unsigned T = sT, CL = sCL, K2 = sK2;
  int st = blockIdx.x * 256 + t;
  unsigned kk[4]; unsigned nl = 0, ne = 0;
#pragma unroll
  for (int l = 0; l < 4; ++l) {
    kk[l] = keys[st + l * 32768];
    nl += (kk[l] < T); ne += (kk[l] == T);
  }
  if (nl) atomicAdd(&totL, nl);
  if (ne) atomicAdd(&totE, ne);
  __syncthreads();
  if (t == 0) { curL = atomicAdd(&ctrl[5], totL); curE = atomicAdd(&ctrl[6], totE); }
  __syncthreads();
  int lane = t & 63;
#pragma unroll
  for (int l = 0; l < 4; ++l) {
    int i = st + l * 32768;
    unsigned k = kk[l];
    bool lt = k < T, eq = k == T;
    unsigned long long ml = __ballot(lt), me = __ballot(eq);
    unsigned wl = __popcll(ml), we = __popcll(me);
    unsigned bl = 0, be = 0;
    if (wl) { if (lane == 0) bl = atomicAdd(&curL, wl); bl = __shfl(bl, 0); }
    if (we) { if (lane == 0) be = atomicAdd(&curE, we); be = __shfl(be, 0); }
    int pos = -1;
    if (lt) pos = (int)(bl + __popcll(ml & ((1ull << lane) - 1ull)));
    else if (eq) {
      unsigned e = be + __popcll(me & ((1ull << lane) - 1ull));
      if (e < K2) pos = (int)(CL + e);
    }
    if (pos >= 0) {
      float x = q[3 * i], y = q[3 * i + 1], z = q[3 * i + 2];
      reps[pos] = make_float4(x, y, z, sumsq_nc(x, y, z));
    }
  }
}

// grid (128, NCHT) x 256: 4 queries/thread, reps staged in LDS -> VGPRs
template <int NCHT>
__global__ __launch_bounds__(256) void k_main(const float* __restrict__ q,
                                              const float4* __restrict__ reps,
                                              float* __restrict__ part) {
  constexpr int RPC = PCNT / NCHT;
  __shared__ float4 lds[RPC];
  int t = threadIdx.x;
  int c = blockIdx.y;
  const float4* rp = reps + c * RPC;
  for (int j = t; j < RPC; j += 256) lds[j] = rp[j];
  int qbase = blockIdx.x * (256 * QPT) + t;
  float qx[QPT], qy[QPT], qz[QPT], mn[QPT];
#pragma unroll
  for (int k = 0; k < QPT; ++k) {
    int i = qbase + k * 256;
    qx[k] = -2.0f * q[3 * i];
    qy[k] = -2.0f * q[3 * i + 1];
    qz[k] = -2.0f * q[3 * i + 2];
    mn[k] = 1e30f;
  }
  __syncthreads();
#pragma unroll 2
  for (int j = 0; j < RPC; j += 4) {
    float4 r0 = lds[j], r1 = lds[j + 1], r2 = lds[j + 2], r3 = lds[j + 3];
#pragma unroll
    for (int k = 0; k < QPT; ++k) {
      float t0 = fmaf(qx[k], r0.x, fmaf(qy[k], r0.y, fmaf(qz[k], r0.z, r0.w)));
      float t1 = fmaf(qx[k], r1.x, fmaf(qy[k], r1.y, fmaf(qz[k], r1.z, r1.w)));
      float t2 = fmaf(qx[k], r2.x, fmaf(qy[k], r2.y, fmaf(qz[k], r2.z, r2.w)));
      float t3 = fmaf(qx[k], r3.x, fmaf(qy[k], r3.y, fmaf(qz[k], r3.z, r3.w)));
      mn[k] = fminf(mn[k], fminf(t0, t1));  // v_min3_f32
      mn[k] = fminf(mn[k], fminf(t2, t3));
    }
  }
#pragma unroll
  for (int k = 0; k < QPT; ++k) part[c * NQ + qbase + k * 256] = mn[k];
}

// 512 blocks: combine chunks + epilogue
template <int NCHT>
__global__ __launch_bounds__(256) void k_reduce(const float* __restrict__ q,
                                               const float* __restrict__ part,
                                               float* __restrict__ out) {
  int i = blockIdx.x * 256 + threadIdx.x;
  float m = part[i];
#pragma unroll
  for (int c = 1; c < NCHT; ++c) m = fminf(m, part[c * NQ + i]);
  float x = q[3 * i], y = q[3 * i + 1], z = q[3 * i + 2];
  float s = sumsq_nc(x, y, z);
  float d = sqrtf(s) - 0.5f;
  float d2 = fmaxf(s + m, 0.0f);
  float nd = (d2 > 0.0f) ? sqrtf(d2) : 0.0f;
  float sg = (d > 0.0f) ? 1.0f : ((d < 0.0f) ? -1.0f : 0.0f);
  out[i] = fminf(nd * sg, d);
}

extern "C" void kernel_launch(void* const* d_in, const int* in_sizes, int n_in,
                              void* d_out, int out_size, void* d_ws, size_t ws_size,
                              hipStream_t stream) {
  const float* q = (const float*)d_in[0];
  float* out = (float*)d_out;
  char* ws = (char*)d_ws;

  unsigned* hist = (unsigned*)(ws + HIST_OFF);
  unsigned* ctrl = (unsigned*)(ws + CTRL_OFF);
  unsigned* keys = (unsigned*)(ws + KEYS_OFF);
  unsigned* cand = (unsigned*)(ws + CAND_OFF);
  float4* reps   = (float4*)(ws + REPS_OFF);
  float* part    = (float*)(ws + PART_OFF);

  hipMemsetAsync(hist, 0, NBIN * 4, stream);
  k_keys<<<128, 256, 0, stream>>>(q, keys, hist, ctrl);
  k_compact1<<<128, 256, 0, stream>>>(keys, hist, ctrl, cand);
  k_repbuild<<<128, 256, 0, stream>>>(q, keys, hist, ctrl, cand, reps);

  size_t need8 = (size_t)PART_OFF + (size_t)8 * NQ * 4;
  if (ws_size >= need8) {
    k_main<8><<<dim3(NQ / (256 * QPT), 8), 256, 0, stream>>>(q, reps, part);
    k_reduce<8><<<NQ / 256, 256, 0, stream>>>(q, part, out);
  } else {
    k_main<4><<<dim3(NQ / (256 * QPT), 4), 256, 0, stream>>>(q, reps, part);
    k_reduce<4><<<NQ / 256, 256, 0, stream>>>(q, part, out);
  }
}